// Round 1
// baseline (294.846 us; speedup 1.0000x reference)
//
#include <hip/hip_runtime.h>
#include <math.h>

// CombinedLoss: 0.5 * dice_loss + 0.5 * CE over [B=8, C=23, H=512, W=512] f32 logits.
// Memory-bound: one fused pass over predictions (193 MB) + targets.

#define NC 23
#define HW_SZ (512 * 512)          // 2^18
#define NPIX (8 * HW_SZ)           // 2^21 pixels
#define NQ 47                      // inter[23] + denom[23] + ce

__device__ __forceinline__ float wave_red(float v) {
#pragma unroll
    for (int off = 32; off > 0; off >>= 1) v += __shfl_down(v, off, 64);
    return v;
}

__global__ __launch_bounds__(256) void cl_main(const float* __restrict__ pred,
                                               const int* __restrict__ tgt,
                                               float* __restrict__ partials, int nb) {
    float inter[NC], denom[NC];
#pragma unroll
    for (int c = 0; c < NC; ++c) { inter[c] = 0.0f; denom[c] = 0.0f; }
    float ce = 0.0f;

    int tid = blockIdx.x * blockDim.x + threadIdx.x;
    int stride = gridDim.x * blockDim.x;

    for (int p = tid; p < NPIX; p += stride) {
        int b = p >> 18;                 // p / HW
        int hw = p & (HW_SZ - 1);        // p % HW
        const float* base = pred + (size_t)b * NC * HW_SZ + hw;

        float l[NC];
#pragma unroll
        for (int c = 0; c < NC; ++c) l[c] = base[(size_t)c * HW_SZ];

        int t = tgt[p];

        float m = l[0];
#pragma unroll
        for (int c = 1; c < NC; ++c) m = fmaxf(m, l[c]);

        // lt = logit at target class (static cndmask chain, no runtime indexing);
        // overwrite l[] with exp(l - m) in the same unrolled loop.
        float s = 0.0f;
        float lt = l[0];
#pragma unroll
        for (int c = 0; c < NC; ++c) {
            lt = (c == t) ? l[c] : lt;
            float e = __expf(l[c] - m);
            l[c] = e;
            s += e;
        }
        float rinv = 1.0f / s;
        float lse = __logf(s);
        ce += (m + lse - lt);            // -log p_t

#pragma unroll
        for (int c = 0; c < NC; ++c) {
            float pc = l[c] * rinv;      // softmax prob for class c
            bool is_t = (c == t);
            inter[c] += is_t ? pc : 0.0f;
            denom[c] += pc + (is_t ? 1.0f : 0.0f);
        }
    }

    // Block-level reduction of 47 quantities: wave shfl-reduce -> LDS -> partials.
    __shared__ float red[4][NQ + 1];
    int lane = threadIdx.x & 63;
    int wv = threadIdx.x >> 6;

#pragma unroll
    for (int c = 0; c < NC; ++c) {
        float v = wave_red(inter[c]);
        if (lane == 0) red[wv][c] = v;
    }
#pragma unroll
    for (int c = 0; c < NC; ++c) {
        float v = wave_red(denom[c]);
        if (lane == 0) red[wv][NC + c] = v;
    }
    {
        float v = wave_red(ce);
        if (lane == 0) red[wv][2 * NC] = v;
    }
    __syncthreads();

    if (threadIdx.x < NQ) {
        float v = red[0][threadIdx.x] + red[1][threadIdx.x] +
                  red[2][threadIdx.x] + red[3][threadIdx.x];
        partials[(size_t)threadIdx.x * nb + blockIdx.x] = v;
    }
}

__global__ __launch_bounds__(1024) void cl_reduce(const float* __restrict__ partials,
                                                  int nb, float* __restrict__ out) {
    __shared__ double res[NQ];
    int lane = threadIdx.x & 63;
    int wv = threadIdx.x >> 6;   // 0..15

    for (int q = wv; q < NQ; q += 16) {
        double acc = 0.0;
        for (int i = lane; i < nb; i += 64) acc += (double)partials[(size_t)q * nb + i];
#pragma unroll
        for (int off = 32; off > 0; off >>= 1) acc += __shfl_down(acc, off, 64);
        if (lane == 0) res[q] = acc;
    }
    __syncthreads();

    if (threadIdx.x == 0) {
        const double S = 1e-5;
        double dice_sum = 0.0;
        for (int c = 0; c < NC; ++c) {
            double dice = (2.0 * res[c] + S) / (res[NC + c] + S);
            dice_sum += (1.0 - dice);
        }
        double dice_loss = dice_sum / (double)NC;
        double ce_mean = res[2 * NC] / (double)NPIX;
        out[0] = (float)(0.5 * dice_loss + 0.5 * ce_mean);
    }
}

extern "C" void kernel_launch(void* const* d_in, const int* in_sizes, int n_in,
                              void* d_out, int out_size, void* d_ws, size_t ws_size,
                              hipStream_t stream) {
    const float* pred = (const float*)d_in[0];
    const int* tgt = (const int*)d_in[1];
    float* out = (float*)d_out;
    float* partials = (float*)d_ws;

    int nb = 1024;  // blocks for main kernel; partials need 47*nb floats
    while (nb > 1 && (size_t)NQ * nb * sizeof(float) > ws_size) nb >>= 1;

    cl_main<<<nb, 256, 0, stream>>>(pred, tgt, partials, nb);
    cl_reduce<<<1, 1024, 0, stream>>>(partials, nb, out);
}